// Round 2
// baseline (160.175 us; speedup 1.0000x reference)
//
#include <hip/hip_runtime.h>

#define MD   4
#define B_   4
#define C_   128
#define H_   128
#define W_   256
#define ND   9            // 2*MD+1 displacements per axis
#define XPT  8            // x pixels per lane (32 lanes cover W)

typedef float float4v __attribute__((ext_vector_type(4)));

__global__ __launch_bounds__(64, 4)
void corr_kernel(const float* __restrict__ t1,
                 const float* __restrict__ t2,
                 float* __restrict__ out) {
    const int lane = threadIdx.x;      // 0..63
    const int half = lane >> 5;        // channel parity: 0 = even ch, 1 = odd ch
    const int lx   = lane & 31;        // x-group 0..31
    const int x0   = lx * XPT;         // 0..248
    const int dy   = blockIdx.x;       // 0..8
    const int y    = blockIdx.y;       // 0..127
    const int b    = blockIdx.z;       // 0..3
    const int yy   = y + dy - MD;      // shifted row (wave-uniform)

    float acc[ND][XPT];
    #pragma unroll
    for (int dx = 0; dx < ND; ++dx)
        #pragma unroll
        for (int j = 0; j < XPT; ++j) acc[dx][j] = 0.0f;

    if (0 <= yy && yy < H_) {
        const bool lm = (lx == 0);     // window extends left of x=0
        const bool rm = (lx == 31);    // window extends right of x=W-1
        const float* p1 = t1 + (((size_t)(b * C_ + half)) * H_ + y ) * W_ + x0;
        const float* p2 = t2 + (((size_t)(b * C_ + half)) * H_ + yy) * W_ + x0;
        const size_t cstride = 2 * (size_t)H_ * W_;   // 2 channels per iter

        for (int c = 0; c < C_ / 2; ++c) {
            // t1: 8 floats of row y, this lane-half's channel
            float a[XPT];
            *(float4v*)&a[0] = *(const float4v*)(p1);
            *(float4v*)&a[4] = *(const float4v*)(p1 + 4);

            // t2 window: x0-4 .. x0+11 (16 floats, all 16B-aligned loads)
            float win[XPT + 2 * MD];
            float4v w0 = {0.f, 0.f, 0.f, 0.f};
            float4v w3 = {0.f, 0.f, 0.f, 0.f};
            if (!lm) w0 = *(const float4v*)(p2 - 4);
            *(float4v*)&win[4]  = *(const float4v*)(p2);
            *(float4v*)&win[8]  = *(const float4v*)(p2 + 4);
            if (!rm) w3 = *(const float4v*)(p2 + 8);
            *(float4v*)&win[0]  = w0;
            *(float4v*)&win[12] = w3;

            #pragma unroll
            for (int dx = 0; dx < ND; ++dx)
                #pragma unroll
                for (int j = 0; j < XPT; ++j)
                    acc[dx][j] = fmaf(a[j], win[dx + j], acc[dx][j]);

            p1 += cstride;
            p2 += cstride;
        }
    }

    // merge the two channel-halves (lane ^ 32)
    #pragma unroll
    for (int dx = 0; dx < ND; ++dx)
        #pragma unroll
        for (int j = 0; j < XPT; ++j)
            acc[dx][j] += __shfl_xor(acc[dx][j], 32);

    // store: half 0 writes j=0..3 at x0, half 1 writes j=4..7 at x0+4
    const float scale = 1.0f / (float)C_;
    #pragma unroll
    for (int dx = 0; dx < ND; ++dx) {
        float4v o;
        #pragma unroll
        for (int j = 0; j < 4; ++j) o[j] = acc[dx][half * 4 + j] * scale;
        const size_t oidx =
            (((size_t)(b * ND * ND) + dy * ND + dx) * H_ + y) * W_ + x0 + half * 4;
        *(float4v*)&out[oidx] = o;
    }
}

extern "C" void kernel_launch(void* const* d_in, const int* in_sizes, int n_in,
                              void* d_out, int out_size, void* d_ws, size_t ws_size,
                              hipStream_t stream) {
    const float* t1 = (const float*)d_in[0];
    const float* t2 = (const float*)d_in[1];
    float* out      = (float*)d_out;
    dim3 grid(ND, H_, B_);
    corr_kernel<<<grid, 64, 0, stream>>>(t1, t2, out);
}

// Round 3
// 90.130 us; speedup vs baseline: 1.7771x; 1.7771x over previous
//
#include <hip/hip_runtime.h>

#define MD   4
#define B_   4
#define C_   128
#define H_   128
#define W_   256
#define ND   9            // 2*MD+1 displacements per axis
#define CC   4            // channels staged per chunk
#define NW   9            // waves per block, one per dy
#define XPT  4            // x pixels per lane (64 lanes cover W)
#define LROW (W_ + 2*MD)  // 264 floats per staged row (4-float zero halos)

typedef float float4v __attribute__((ext_vector_type(4)));

__global__ __launch_bounds__(NW * 64, 2)
void corr_kernel(const float* __restrict__ t1,
                 const float* __restrict__ t2,
                 float* __restrict__ out) {
    __shared__ __align__(16) float t2s[2][CC][ND][LROW];   // 76032 B

    const int tid  = threadIdx.x;
    const int lane = tid & 63;
    const int w    = tid >> 6;                 // wave id == dy
    // XCD swizzle: 512 blocks -> XCD k gets 64 consecutive (b,y) values
    const int bid  = blockIdx.x;
    const int swz  = (bid & 7) * 64 + (bid >> 3);
    const int y    = swz & (H_ - 1);
    const int b    = swz >> 7;
    const int x0   = lane * XPT;               // 0..252
    const int myy  = y + w - MD;               // this wave's shifted row
    const bool live = (0 <= myy) && (myy < H_);

    // Zero the x-halos of every row slot in both buffers (once; never
    // overwritten — staging writes only bytes [16, 4112+16) of each row).
    for (int idx = tid; idx < 2 * CC * ND; idx += NW * 64) {
        const int buf = idx / (CC * ND);
        const int s   = idx % (CC * ND);
        const int c   = s / ND, r = s % ND;
        #pragma unroll
        for (int k = 0; k < MD; ++k) {
            t2s[buf][c][r][k]           = 0.0f;
            t2s[buf][c][r][W_ + MD + k] = 0.0f;
        }
    }

    float acc[ND][XPT];
    #pragma unroll
    for (int dx = 0; dx < ND; ++dx)
        #pragma unroll
        for (int j = 0; j < XPT; ++j) acc[dx][j] = 0.0f;

    const float* t1base = t1 + ((size_t)(b * C_) * H_ + y) * W_ + x0;

    // stage CC channels x 9 rows into buffer `buf`; wave w owns 4 row-slots
    auto STAGE = [&](int buf, int c0) {
        #pragma unroll
        for (int i = 0; i < (CC * ND) / NW; ++i) {
            const int s  = w * ((CC * ND) / NW) + i;
            const int c  = s / ND;
            const int r  = s % ND;
            const int yy = y + r - MD;                  // wave-uniform
            if (0 <= yy && yy < H_) {
                const float* src =
                    t2 + (((size_t)(b * C_ + c0 + c) * H_ + yy) * W_) + lane * 4;
                __builtin_amdgcn_global_load_lds(
                    (const __attribute__((address_space(1))) unsigned int*)src,
                    (__attribute__((address_space(3))) unsigned int*)&t2s[buf][c][r][MD],
                    16, 0, 0);
            }
            // OOB rows: never staged, never read (live==false for that wave)
        }
    };

    auto COMPUTE = [&](int buf, int c0) {
        if (live) {
            #pragma unroll
            for (int cc = 0; cc < CC; ++cc) {
                const float4v t1v =
                    *(const float4v*)(t1base + (size_t)(c0 + cc) * H_ * W_);
                const float* row = &t2s[buf][cc][w][x0];  // idx x0 .. x0+11
                float win[XPT + 2 * MD];
                *(float4v*)&win[0] = *(const float4v*)&row[0];
                *(float4v*)&win[4] = *(const float4v*)&row[4];
                *(float4v*)&win[8] = *(const float4v*)&row[8];
                #pragma unroll
                for (int dx = 0; dx < ND; ++dx)
                    #pragma unroll
                    for (int j = 0; j < XPT; ++j)
                        acc[dx][j] = fmaf(t1v[j], win[dx + j], acc[dx][j]);
            }
        }
    };

    STAGE(0, 0);
    __syncthreads();                            // buf0 ready (vmcnt drained)
    for (int c0 = 0; c0 < C_; c0 += 2 * CC) {
        STAGE(1, c0 + CC);                      // in flight during compute
        COMPUTE(0, c0);
        __syncthreads();                        // buf1 ready; buf0 free
        if (c0 + 2 * CC < C_) STAGE(0, c0 + 2 * CC);
        COMPUTE(1, c0 + CC);
        __syncthreads();                        // buf0 ready; buf1 free
    }

    const float scale = 1.0f / (float)C_;
    #pragma unroll
    for (int dx = 0; dx < ND; ++dx) {
        float4v o;
        #pragma unroll
        for (int j = 0; j < XPT; ++j) o[j] = acc[dx][j] * scale;
        const size_t oidx =
            (((size_t)(b * ND * ND) + w * ND + dx) * H_ + y) * W_ + x0;
        *(float4v*)&out[oidx] = o;
    }
}

extern "C" void kernel_launch(void* const* d_in, const int* in_sizes, int n_in,
                              void* d_out, int out_size, void* d_ws, size_t ws_size,
                              hipStream_t stream) {
    const float* t1 = (const float*)d_in[0];
    const float* t2 = (const float*)d_in[1];
    float* out      = (float*)d_out;
    corr_kernel<<<dim3(B_ * H_), NW * 64, 0, stream>>>(t1, t2, out);
}

// Round 5
// 77.214 us; speedup vs baseline: 2.0744x; 1.1673x over previous
//
#include <hip/hip_runtime.h>

#define MD   4
#define B_   4
#define C_   128
#define H_   128
#define W_   256
#define ND   9            // 2*MD+1 displacements per axis
#define NW   9            // waves per block, one per dy
#define XPT  4            // x pixels per lane (64 lanes cover W)

typedef float float4v __attribute__((ext_vector_type(4)));

// No LDS, no barriers, no inline asm: each lane loads its own float4 of t2
// and gets the +/-4-pixel halo from neighbor lanes via shfl. All memory ops
// are plain register loads -> compiler software-pipelines the channel loop.
__global__ __launch_bounds__(NW * 64, 5)
void corr_kernel(const float* __restrict__ t1,
                 const float* __restrict__ t2,
                 float* __restrict__ out) {
    const int tid  = threadIdx.x;
    const int lane = tid & 63;
    const int w    = tid >> 6;                 // wave id == dy
    const int bid  = blockIdx.x;               // XCD swizzle (512 = 8*64)
    const int swz  = (bid & 7) * 64 + (bid >> 3);
    const int y    = swz & (H_ - 1);
    const int b    = swz >> 7;
    const int x0   = lane * XPT;               // 0..252
    const int yy   = y + w - MD;               // this wave's shifted t2 row
    const float scale = 1.0f / (float)C_;

    if (yy < 0 || yy >= H_) {                  // zero-pad region: output = 0
        float4v z = {0.f, 0.f, 0.f, 0.f};
        #pragma unroll
        for (int dx = 0; dx < ND; ++dx) {
            const size_t oidx =
                (((size_t)(b * ND * ND) + w * ND + dx) * H_ + y) * W_ + x0;
            *(float4v*)&out[oidx] = z;
        }
        return;
    }

    float acc[ND][XPT];
    #pragma unroll
    for (int dx = 0; dx < ND; ++dx)
        #pragma unroll
        for (int j = 0; j < XPT; ++j) acc[dx][j] = 0.0f;

    const float* p1 = t1 + (((size_t)(b * C_)) * H_ + y ) * W_ + x0;
    const float* p2 = t2 + (((size_t)(b * C_)) * H_ + yy) * W_ + x0;
    const size_t chstr = (size_t)H_ * W_;

    const bool lm = (lane == 0);    // window extends left of x=0  -> pad 0
    const bool rm = (lane == 63);   // window extends right of W-1 -> pad 0

    #pragma unroll 2
    for (int c = 0; c < C_; ++c) {
        const float4v a = *(const float4v*)(p1 + (size_t)c * chstr);
        const float4v v = *(const float4v*)(p2 + (size_t)c * chstr);

        // win[k] = t2 value at x = x0 - 4 + k, k = 0..11
        float win[XPT + 2 * MD];
        #pragma unroll
        for (int k = 0; k < 4; ++k) {
            const float up = __shfl_up(v[k], 1);    // lane-1's v[k]
            const float dn = __shfl_down(v[k], 1);  // lane+1's v[k]
            win[k]     = lm ? 0.0f : up;
            win[4 + k] = v[k];
            win[8 + k] = rm ? 0.0f : dn;
        }

        #pragma unroll
        for (int dx = 0; dx < ND; ++dx)
            #pragma unroll
            for (int j = 0; j < XPT; ++j)
                acc[dx][j] = fmaf(a[j], win[dx + j], acc[dx][j]);
    }

    #pragma unroll
    for (int dx = 0; dx < ND; ++dx) {
        float4v o;
        #pragma unroll
        for (int j = 0; j < XPT; ++j) o[j] = acc[dx][j] * scale;
        const size_t oidx =
            (((size_t)(b * ND * ND) + w * ND + dx) * H_ + y) * W_ + x0;
        *(float4v*)&out[oidx] = o;
    }
}

extern "C" void kernel_launch(void* const* d_in, const int* in_sizes, int n_in,
                              void* d_out, int out_size, void* d_ws, size_t ws_size,
                              hipStream_t stream) {
    const float* t1 = (const float*)d_in[0];
    const float* t2 = (const float*)d_in[1];
    float* out      = (float*)d_out;
    corr_kernel<<<dim3(B_ * H_), NW * 64, 0, stream>>>(t1, t2, out);
}